// Round 2
// baseline (170.033 us; speedup 1.0000x reference)
//
#include <hip/hip_runtime.h>
#include <hip/hip_bf16.h>

#define DI __device__ __forceinline__

typedef float f32x4 __attribute__((ext_vector_type(4)));
typedef float f32x16 __attribute__((ext_vector_type(16)));
typedef short s16x8 __attribute__((ext_vector_type(8)));
typedef unsigned short u16x4 __attribute__((ext_vector_type(4)));

// Problem constants: N=2048, B=2, C=1024, H=16, HD=64, M=B*N=4096.

DI unsigned short f2bf(float x) {            // f32 -> bf16 RNE
  union { float f; unsigned u; } v; v.f = x;
  unsigned r = 0x7fffu + ((v.u >> 16) & 1u);
  return (unsigned short)((v.u + r) >> 16);
}

DI f32x16 zero16() {
  f32x16 z;
#pragma unroll
  for (int i = 0; i < 16; ++i) z[i] = 0.f;
  return z;
}

DI void gll16(const void* g, void* l) {      // async global->LDS, 16B/lane
  __builtin_amdgcn_global_load_lds(
      (const __attribute__((address_space(1))) void*)g,
      (__attribute__((address_space(3))) void*)l, 16, 0, 0);
}

DI f32x16 mfma32(s16x8 a, s16x8 b, f32x16 c) {
  return __builtin_amdgcn_mfma_f32_32x32x16_bf16(a, b, c, 0, 0, 0);
}

// ---------------- weight transpose + bf16 convert ----------------
// WT[n][k] = bf16(W[k][n]); K=1024 always. Grid: 512(Wq)+512(Wp)+32(Wk)+32(Wv).
__global__ __launch_bounds__(256) void wconv_kernel(
    const float* __restrict__ Wq, const float* __restrict__ Wk,
    const float* __restrict__ Wv, const float* __restrict__ Wp,
    unsigned short* __restrict__ WqT, unsigned short* __restrict__ WkT,
    unsigned short* __restrict__ WvT, unsigned short* __restrict__ WpT)
{
  int bid = blockIdx.x;
  const float* W; unsigned short* WT; int Ncols; int base;
  if (bid < 512)       { W = Wq; WT = WqT; Ncols = 1024; base = bid; }
  else if (bid < 1024) { W = Wp; WT = WpT; Ncols = 1024; base = bid - 512; }
  else if (bid < 1056) { W = Wk; WT = WkT; Ncols = 64;   base = bid - 1024; }
  else                 { W = Wv; WT = WvT; Ncols = 64;   base = bid - 1056; }
  int nb = base >> 5, kb = base & 31;              // 64-n x 32-k tile
  int n = nb * 64 + (threadIdx.x & 63);
  int k = kb * 32 + (threadIdx.x >> 6) * 8;
  union { unsigned short s[8]; s16x8 v; } u;
#pragma unroll
  for (int i = 0; i < 8; ++i) u.s[i] = f2bf(W[(size_t)(k + i) * Ncols + n]);
  *(s16x8*)(WT + (size_t)n * 1024 + k) = u.v;
}

// ---------------- GEMM: C[M=4096][Nout] = A[4096][1024] @ WT^T (+bias) ------
// MODE 0: q-proj  (A=query f32, seq-first remap, out bf16 * scale), BN=128
// MODE 1: k/v-proj (blockIdx.y: 0 -> key remap -> kproj; 1 -> value -> vprojT)
// MODE 2: out-proj (A=x bf16 via global_load_lds, out f32 remapped to (N,B,C))
template<int BN, int MODE>
__global__ __launch_bounds__(256) void gemm_kernel(
    const void* __restrict__ Ap, const unsigned short* __restrict__ Btp,
    const float* __restrict__ biasp, void* __restrict__ Cpv,
    const void* __restrict__ Ap2, const unsigned short* __restrict__ Btp2,
    const float* __restrict__ bias2, void* __restrict__ Cpv2,
    float scale)
{
  __shared__ unsigned short Asub[128 * 64];   // [m][k] 16KB
  __shared__ unsigned short Bsub[BN * 64];    // [n][k]

  const int tid = threadIdx.x;
  const int lane = tid & 63, wave = tid >> 6;
  const int lq = lane & 31, hi = lane >> 5;
  const int wr = wave >> 1, wc = wave & 1;    // 2x2 wave grid
  constexpr int WCOLS = BN / 2;
  constexpr int NJ = WCOLS / 32;

  const void* A_ = Ap; const unsigned short* Bt = Btp;
  const float* bias = biasp; void* Cp = Cpv;
  bool vmode = false;
  if constexpr (MODE == 1) {
    if (blockIdx.y != 0) { A_ = Ap2; Bt = Btp2; bias = bias2; Cp = Cpv2; vmode = true; }
  }
  const int row0 = blockIdx.x * 128;
  const int col0 = (MODE == 1) ? 0 : blockIdx.y * BN;

  const float* Af = (const float*)A_;
  const unsigned short* Ab = (const unsigned short*)A_;
  const bool remap = (MODE == 0) || (MODE == 1 && !vmode);  // (N,B,C) -> (B,N,C) row remap

  f32x16 acc[2][NJ];
#pragma unroll
  for (int mi = 0; mi < 2; ++mi)
#pragma unroll
    for (int nj = 0; nj < NJ; ++nj) acc[mi][nj] = zero16();

  const int ar = tid >> 4;
  const int ac = (tid & 15) * 4;

  for (int kt = 0; kt < 16; ++kt) {
    const int k0 = kt * 64;
    __syncthreads();
    if constexpr (MODE != 2) {
      // reg-staged A: f32 -> bf16 -> LDS
#pragma unroll
      for (int p = 0; p < 8; ++p) {
        int r = p * 16 + ar;
        int gm = row0 + r;
        size_t grow = remap ? (size_t)((gm & 2047) * 2 + (gm >> 11)) * 1024
                            : (size_t)gm * 1024;
        f32x4 v = *(const f32x4*)(Af + grow + k0 + ac);
        u16x4 hx = { f2bf(v.x), f2bf(v.y), f2bf(v.z), f2bf(v.w) };
        *(u16x4*)(&Asub[r * 64 + ac]) = hx;
      }
    } else {
#pragma unroll
      for (int i = 0; i < 4; ++i) {
        int o = i * 4096 + tid * 16;
        int r = o >> 7, c = (o & 127) >> 1;
        gll16(Ab + (size_t)(row0 + r) * 1024 + k0 + c,
              (char*)Asub + i * 4096 + wave * 1024);
      }
    }
#pragma unroll
    for (int i = 0; i < BN / 32; ++i) {
      int o = i * 4096 + tid * 16;
      int r = o >> 7, c = (o & 127) >> 1;
      gll16(Bt + (size_t)(col0 + r) * 1024 + k0 + c,
            (char*)Bsub + i * 4096 + wave * 1024);
    }
    __syncthreads();
#pragma unroll
    for (int s = 0; s < 4; ++s) {
      s16x8 af[2]; s16x8 bfr[NJ];
#pragma unroll
      for (int mi = 0; mi < 2; ++mi)
        af[mi] = *(const s16x8*)((const char*)Asub +
                  (wr * 64 + mi * 32 + lq) * 128 + s * 32 + hi * 16);
#pragma unroll
      for (int nj = 0; nj < NJ; ++nj)
        bfr[nj] = *(const s16x8*)((const char*)Bsub +
                  (wc * WCOLS + nj * 32 + lq) * 128 + s * 32 + hi * 16);
#pragma unroll
      for (int mi = 0; mi < 2; ++mi)
#pragma unroll
        for (int nj = 0; nj < NJ; ++nj)
          acc[mi][nj] = mfma32(af[mi], bfr[nj], acc[mi][nj]);
    }
  }

  // epilogue; C-layout: col = lane&31, row = (e&3) + 8*(e>>2) + 4*(lane>>5)
#pragma unroll
  for (int mi = 0; mi < 2; ++mi)
#pragma unroll
  for (int nj = 0; nj < NJ; ++nj) {
    int col = col0 + wc * WCOLS + nj * 32 + lq;
    float bv = bias[col];
#pragma unroll
    for (int g = 0; g < 4; ++g)
#pragma unroll
    for (int r = 0; r < 4; ++r) {
      int e = g * 4 + r;
      int row = row0 + wr * 64 + mi * 32 + r + 8 * g + 4 * hi;
      float val = acc[mi][nj][e] + bv;
      if constexpr (MODE == 0) {
        ((unsigned short*)Cp)[(size_t)row * 1024 + col] = f2bf(val * scale);
      } else if constexpr (MODE == 1) {
        if (!vmode)
          ((unsigned short*)Cp)[(size_t)row * 64 + col] = f2bf(val);
        else  // vprojT[b][d=col][n]
          ((unsigned short*)Cp)[(size_t)(row >> 11) * (64 * 2048) +
                                (size_t)col * 2048 + (row & 2047)] = f2bf(val);
      } else { // out (N,B,C) f32
        ((float*)Cp)[(size_t)(row & 2047) * 2048 + (size_t)(row >> 11) * 1024 + col] = val;
      }
    }
  }
}

// ---------------- flash attention (MQA), swapped-operand 32x32 MFMA ---------
// CONSERVATIVE VERSION (round 2): reg-staged K/V into PADDED LDS (no swizzle,
// no global_load_lds here), P redistribution via per-wave LDS round-trip
// (no cvt_pk / cross-lane shuffle). 8 waves x 32 q-rows, KVBLK=64.
// S^T = mfma(K, Q): lane owns q = lane&31 -> lane-local online softmax.
// PV: X^T = mfma(V^T, P^T) with P^T read back from LDS.
__global__ __launch_bounds__(512) void attn_kernel(
    const unsigned short* __restrict__ qp, const unsigned short* __restrict__ kp,
    const unsigned short* __restrict__ vpt, unsigned short* __restrict__ xout)
{
  constexpr int KSTR = 72;                     // 64 + 8 pad (shorts)
  __shared__ unsigned short Ks[64 * KSTR];     // [kv][d]
  __shared__ unsigned short Vt[64 * KSTR];     // [d][kv]
  __shared__ unsigned short Pl[8 * 32 * KSTR]; // per-wave P[q][kv]

  const int tid = threadIdx.x;
  const int lane = tid & 63, wave = tid >> 6;
  const int lq = lane & 31, hi = lane >> 5;
  const int b = blockIdx.y >> 4, h = blockIdx.y & 15;
  const int q0 = blockIdx.x * 256 + wave * 32;
  const size_t qrow = (size_t)(b * 2048 + q0 + lq);

  unsigned short* Pw = Pl + wave * (32 * KSTR);

  s16x8 qf[4];  // Q as B-operand: lane holds Q[q][d = s*16 + 8*hi .. +8)
#pragma unroll
  for (int s = 0; s < 4; ++s)
    qf[s] = *(const s16x8*)(qp + qrow * 1024 + h * 64 + s * 16 + hi * 8);

  f32x16 xacc0 = zero16(), xacc1 = zero16();
  float mrun = -1e30f, ssum = 0.f;

  const unsigned short* kb = kp + (size_t)b * (2048 * 64);
  const unsigned short* vb = vpt + (size_t)b * (64 * 2048);

  const int srow = tid >> 3;            // 0..63
  const int scol = (tid & 7) * 8;       // shorts, 16B per thread

  for (int t = 0; t < 32; ++t) {
    __syncthreads();   // guard LDS reuse (K/V/P) from previous iteration
    {
      s16x8 kv_ = *(const s16x8*)(kb + (size_t)(t * 64 + srow) * 64 + scol);
      s16x8 vv_ = *(const s16x8*)(vb + (size_t)srow * 2048 + t * 64 + scol);
      *(s16x8*)(Ks + srow * KSTR + scol) = kv_;
      *(s16x8*)(Vt + srow * KSTR + scol) = vv_;
    }
    __syncthreads();

    // S^T[kv][q], two 32-kv fragments
    f32x16 sacc0 = zero16(), sacc1 = zero16();
#pragma unroll
    for (int s = 0; s < 4; ++s) {
      int c = s * 16 + hi * 8;
      s16x8 kf0 = *(const s16x8*)(Ks + lq * KSTR + c);
      s16x8 kf1 = *(const s16x8*)(Ks + (32 + lq) * KSTR + c);
      sacc0 = mfma32(kf0, qf[s], sacc0);
      sacc1 = mfma32(kf1, qf[s], sacc1);
    }

    // online softmax in exp2 domain (scale folded into q-proj)
    float tm = sacc0[0];
#pragma unroll
    for (int e = 1; e < 16; ++e) tm = fmaxf(tm, sacc0[e]);
#pragma unroll
    for (int e = 0; e < 16; ++e) tm = fmaxf(tm, sacc1[e]);
    tm = fmaxf(tm, __shfl_xor(tm, 32));
    float mnew = fmaxf(mrun, tm);
    float alpha = __builtin_amdgcn_exp2f(mrun - mnew);

    f32x16 p0, p1;
    float tsum = 0.f;
#pragma unroll
    for (int e = 0; e < 16; ++e) { p0[e] = __builtin_amdgcn_exp2f(sacc0[e] - mnew); tsum += p0[e]; }
#pragma unroll
    for (int e = 0; e < 16; ++e) { p1[e] = __builtin_amdgcn_exp2f(sacc1[e] - mnew); tsum += p1[e]; }
    tsum += __shfl_xor(tsum, 32);
    ssum = ssum * alpha + tsum;
    mrun = mnew;
#pragma unroll
    for (int e = 0; e < 16; ++e) { xacc0[e] *= alpha; xacc1[e] *= alpha; }

    // P round-trip through LDS: lane owns q-row lq of this wave's P tile.
    // sacc element e corresponds to kv = (e&3) + 8*(e>>2) + 4*hi (+32 for p1).
#pragma unroll
    for (int g = 0; g < 4; ++g) {
      u16x4 w0 = { f2bf(p0[4*g+0]), f2bf(p0[4*g+1]), f2bf(p0[4*g+2]), f2bf(p0[4*g+3]) };
      *(u16x4*)(Pw + lq * KSTR + 8 * g + 4 * hi) = w0;
      u16x4 w1 = { f2bf(p1[4*g+0]), f2bf(p1[4*g+1]), f2bf(p1[4*g+2]), f2bf(p1[4*g+3]) };
      *(u16x4*)(Pw + lq * KSTR + 32 + 8 * g + 4 * hi) = w1;
    }
    __syncthreads();   // P visible to both lane-halves

    // X^T += V^T @ P^T  (two 32-d fragments)
#pragma unroll
    for (int kvs = 0; kvs < 4; ++kvs) {
      int c = kvs * 16 + hi * 8;
      s16x8 vf0 = *(const s16x8*)(Vt + lq * KSTR + c);
      s16x8 vf1 = *(const s16x8*)(Vt + (32 + lq) * KSTR + c);
      s16x8 pf  = *(const s16x8*)(Pw + lq * KSTR + c);
      xacc0 = mfma32(vf0, pf, xacc0);
      xacc1 = mfma32(vf1, pf, xacc1);
    }
  }

  float inv = 1.0f / ssum;
#pragma unroll
  for (int dj = 0; dj < 2; ++dj) {
    const f32x16 xa = dj ? xacc1 : xacc0;
#pragma unroll
    for (int g = 0; g < 4; ++g) {
      u16x4 o4;
#pragma unroll
      for (int r = 0; r < 4; ++r) o4[r] = f2bf(xa[g * 4 + r] * inv);
      int d0 = dj * 32 + 8 * g + 4 * hi;
      *(u16x4*)(xout + qrow * 1024 + h * 64 + d0) = o4;
    }
  }
}

// -----------------------------------------------------------------------------
extern "C" void kernel_launch(void* const* d_in, const int* in_sizes, int n_in,
                              void* d_out, int out_size, void* d_ws, size_t ws_size,
                              hipStream_t stream)
{
  const float* query = (const float*)d_in[0];
  const float* key   = (const float*)d_in[1];
  const float* value = (const float*)d_in[2];
  const float* Wq = (const float*)d_in[4];
  const float* bq = (const float*)d_in[5];
  const float* Wk = (const float*)d_in[6];
  const float* bk = (const float*)d_in[7];
  const float* Wv = (const float*)d_in[8];
  const float* bv = (const float*)d_in[9];
  const float* Wp = (const float*)d_in[10];
  const float* bp = (const float*)d_in[11];

  char* ws = (char*)d_ws;
  unsigned short* WqT    = (unsigned short*)(ws);
  unsigned short* WpT    = (unsigned short*)(ws + (2u << 20));
  unsigned short* WkT    = (unsigned short*)(ws + (4u << 20));
  unsigned short* WvT    = (unsigned short*)(ws + (4u << 20) + (128u << 10));
  unsigned short* kproj  = (unsigned short*)(ws + (5u << 20));
  unsigned short* vprojT = (unsigned short*)(ws + (5u << 20) + (512u << 10));
  unsigned short* qproj  = (unsigned short*)(ws + (6u << 20));
  unsigned short* xbuf   = (unsigned short*)(ws + (14u << 20));

  wconv_kernel<<<dim3(1088), 256, 0, stream>>>(Wq, Wk, Wv, Wp, WqT, WkT, WvT, WpT);

  const float qscale = 0.18033688011112042f;  // hd^-0.5 * log2(e)
  gemm_kernel<128, 0><<<dim3(32, 8), 256, 0, stream>>>(
      query, WqT, bq, qproj, nullptr, nullptr, nullptr, nullptr, qscale);
  gemm_kernel<64, 1><<<dim3(32, 2), 256, 0, stream>>>(
      key, WkT, bk, kproj, value, WvT, bv, vprojT, 1.0f);
  attn_kernel<<<dim3(8, 32), 512, 0, stream>>>(qproj, kproj, vprojT, xbuf);
  gemm_kernel<128, 2><<<dim3(32, 8), 256, 0, stream>>>(
      xbuf, WpT, bp, d_out, nullptr, nullptr, nullptr, nullptr, 1.0f);
}

// Round 3
// 150.561 us; speedup vs baseline: 1.1293x; 1.1293x over previous
//
#include <hip/hip_runtime.h>
#include <hip/hip_bf16.h>

#define DI __device__ __forceinline__

typedef float f32x4 __attribute__((ext_vector_type(4)));
typedef float f32x16 __attribute__((ext_vector_type(16)));
typedef short s16x8 __attribute__((ext_vector_type(8)));
typedef unsigned short u16x4 __attribute__((ext_vector_type(4)));
typedef unsigned long long u64;

// Problem constants: N=2048, B=2, C=1024, H=16, HD=64, M=B*N=4096.

DI unsigned short f2bf(float x) {            // f32 -> bf16 RNE (epilogue use)
  union { float f; unsigned u; } v; v.f = x;
  unsigned r = 0x7fffu + ((v.u >> 16) & 1u);
  return (unsigned short)((v.u + r) >> 16);
}

DI unsigned cvtpk(float lo, float hi) {      // packed f32x2 -> bf16x2 (RNE)
  unsigned u;
  asm("v_cvt_pk_bf16_f32 %0, %1, %2" : "=v"(u) : "v"(lo), "v"(hi));
  return u;
}

DI f32x16 zero16() {
  f32x16 z;
#pragma unroll
  for (int i = 0; i < 16; ++i) z[i] = 0.f;
  return z;
}

DI float max16(const f32x16& a) {            // 4-level tree
  float m0 = fmaxf(a[0], a[1]),  m1 = fmaxf(a[2], a[3]);
  float m2 = fmaxf(a[4], a[5]),  m3 = fmaxf(a[6], a[7]);
  float m4 = fmaxf(a[8], a[9]),  m5 = fmaxf(a[10], a[11]);
  float m6 = fmaxf(a[12], a[13]), m7 = fmaxf(a[14], a[15]);
  m0 = fmaxf(m0, m1); m2 = fmaxf(m2, m3); m4 = fmaxf(m4, m5); m6 = fmaxf(m6, m7);
  return fmaxf(fmaxf(m0, m2), fmaxf(m4, m6));
}

DI float sum16(const f32x16& a) {            // 4-level tree
  float s0 = a[0] + a[1],  s1 = a[2] + a[3];
  float s2 = a[4] + a[5],  s3 = a[6] + a[7];
  float s4 = a[8] + a[9],  s5 = a[10] + a[11];
  float s6 = a[12] + a[13], s7 = a[14] + a[15];
  s0 += s1; s2 += s3; s4 += s5; s6 += s7;
  return (s0 + s2) + (s4 + s6);
}

DI void gll16(const void* g, void* l) {      // async global->LDS, 16B/lane
  __builtin_amdgcn_global_load_lds(
      (const __attribute__((address_space(1))) void*)g,
      (__attribute__((address_space(3))) void*)l, 16, 0, 0);
}

DI f32x16 mfma32(s16x8 a, s16x8 b, f32x16 c) {
  return __builtin_amdgcn_mfma_f32_32x32x16_bf16(a, b, c, 0, 0, 0);
}

// ---------------- weight transpose + bf16 convert ----------------
// WT[n][k] = bf16(W[k][n]); K=1024 always. Grid: 512(Wq)+512(Wp)+32(Wk)+32(Wv).
__global__ __launch_bounds__(256) void wconv_kernel(
    const float* __restrict__ Wq, const float* __restrict__ Wk,
    const float* __restrict__ Wv, const float* __restrict__ Wp,
    unsigned short* __restrict__ WqT, unsigned short* __restrict__ WkT,
    unsigned short* __restrict__ WvT, unsigned short* __restrict__ WpT)
{
  int bid = blockIdx.x;
  const float* W; unsigned short* WT; int Ncols; int base;
  if (bid < 512)       { W = Wq; WT = WqT; Ncols = 1024; base = bid; }
  else if (bid < 1024) { W = Wp; WT = WpT; Ncols = 1024; base = bid - 512; }
  else if (bid < 1056) { W = Wk; WT = WkT; Ncols = 64;   base = bid - 1024; }
  else                 { W = Wv; WT = WvT; Ncols = 64;   base = bid - 1056; }
  int nb = base >> 5, kb = base & 31;              // 64-n x 32-k tile
  int n = nb * 64 + (threadIdx.x & 63);
  int k = kb * 32 + (threadIdx.x >> 6) * 8;
  float f[8];
#pragma unroll
  for (int i = 0; i < 8; ++i) f[i] = W[(size_t)(k + i) * Ncols + n];
  union { unsigned u[4]; s16x8 v; } x;
#pragma unroll
  for (int i = 0; i < 4; ++i) x.u[i] = cvtpk(f[2 * i], f[2 * i + 1]);
  *(s16x8*)(WT + (size_t)n * 1024 + k) = x.v;
}

// ---------------- GEMM: C[M=4096][Nout] = A[4096][1024] @ WT^T (+bias) ------
// MODE 0: q-proj  (A=query f32, seq-first remap, out bf16 * scale)
// MODE 1: k/v-proj (blockIdx.y: 0 -> key remap -> kproj; 1 -> value -> vprojT)
// MODE 2: out-proj (A=x bf16 via global_load_lds, out f32 remapped to (N,B,C))
template<int BM, int BN, int MODE>
__global__ __launch_bounds__(256) void gemm_kernel(
    const void* __restrict__ Ap, const unsigned short* __restrict__ Btp,
    const float* __restrict__ biasp, void* __restrict__ Cpv,
    const void* __restrict__ Ap2, const unsigned short* __restrict__ Btp2,
    const float* __restrict__ bias2, void* __restrict__ Cpv2,
    float scale)
{
  __shared__ unsigned short Asub[BM * 64];   // [m][k]
  __shared__ unsigned short Bsub[BN * 64];   // [n][k]

  const int tid = threadIdx.x;
  const int lane = tid & 63, wave = tid >> 6;
  const int lq = lane & 31, hi = lane >> 5;
  const int wr = wave >> 1, wc = wave & 1;    // 2x2 wave grid
  constexpr int WROWS = BM / 2;
  constexpr int WCOLS = BN / 2;
  constexpr int MI = WROWS / 32;
  constexpr int NJ = WCOLS / 32;

  const void* A_ = Ap; const unsigned short* Bt = Btp;
  const float* bias = biasp; void* Cp = Cpv;
  bool vmode = false;
  if constexpr (MODE == 1) {
    if (blockIdx.y != 0) { A_ = Ap2; Bt = Btp2; bias = bias2; Cp = Cpv2; vmode = true; }
  }
  const int row0 = blockIdx.x * BM;
  const int col0 = (MODE == 1) ? 0 : blockIdx.y * BN;

  const float* Af = (const float*)A_;
  const unsigned short* Ab = (const unsigned short*)A_;
  const bool remap = (MODE == 0) || (MODE == 1 && !vmode);  // (N,B,C) -> (B,N,C) row remap

  f32x16 acc[MI][NJ];
#pragma unroll
  for (int mi = 0; mi < MI; ++mi)
#pragma unroll
    for (int nj = 0; nj < NJ; ++nj) acc[mi][nj] = zero16();

  const int ar = tid >> 4;
  const int ac = (tid & 15) * 4;

  for (int kt = 0; kt < 16; ++kt) {
    const int k0 = kt * 64;
    __syncthreads();
    if constexpr (MODE != 2) {
      // reg-staged A: f32 -> bf16 (cvt_pk) -> LDS
#pragma unroll
      for (int p = 0; p < BM / 16; ++p) {
        int r = p * 16 + ar;
        int gm = row0 + r;
        size_t grow = remap ? (size_t)((gm & 2047) * 2 + (gm >> 11)) * 1024
                            : (size_t)gm * 1024;
        f32x4 v = *(const f32x4*)(Af + grow + k0 + ac);
        u64 w = ((u64)cvtpk(v.z, v.w) << 32) | cvtpk(v.x, v.y);
        *(u64*)(&Asub[r * 64 + ac]) = w;
      }
    } else {
#pragma unroll
      for (int i = 0; i < BM / 32; ++i) {
        int o = i * 4096 + tid * 16;
        int r = o >> 7, c = (o & 127) >> 1;
        gll16(Ab + (size_t)(row0 + r) * 1024 + k0 + c,
              (char*)Asub + i * 4096 + wave * 1024);
      }
    }
#pragma unroll
    for (int i = 0; i < BN / 32; ++i) {
      int o = i * 4096 + tid * 16;
      int r = o >> 7, c = (o & 127) >> 1;
      gll16(Bt + (size_t)(col0 + r) * 1024 + k0 + c,
            (char*)Bsub + i * 4096 + wave * 1024);
    }
    __syncthreads();
#pragma unroll
    for (int s = 0; s < 4; ++s) {
      s16x8 af[MI]; s16x8 bfr[NJ];
#pragma unroll
      for (int mi = 0; mi < MI; ++mi)
        af[mi] = *(const s16x8*)((const char*)Asub +
                  (wr * WROWS + mi * 32 + lq) * 128 + s * 32 + hi * 16);
#pragma unroll
      for (int nj = 0; nj < NJ; ++nj)
        bfr[nj] = *(const s16x8*)((const char*)Bsub +
                  (wc * WCOLS + nj * 32 + lq) * 128 + s * 32 + hi * 16);
#pragma unroll
      for (int mi = 0; mi < MI; ++mi)
#pragma unroll
        for (int nj = 0; nj < NJ; ++nj)
          acc[mi][nj] = mfma32(af[mi], bfr[nj], acc[mi][nj]);
    }
  }

  // epilogue; C-layout: col = lane&31, row = (e&3) + 8*(e>>2) + 4*(lane>>5)
#pragma unroll
  for (int mi = 0; mi < MI; ++mi)
#pragma unroll
  for (int nj = 0; nj < NJ; ++nj) {
    int col = col0 + wc * WCOLS + nj * 32 + lq;
    float bv = bias[col];
#pragma unroll
    for (int g = 0; g < 4; ++g)
#pragma unroll
    for (int r = 0; r < 4; ++r) {
      int e = g * 4 + r;
      int row = row0 + wr * WROWS + mi * 32 + r + 8 * g + 4 * hi;
      float val = acc[mi][nj][e] + bv;
      if constexpr (MODE == 0) {
        ((unsigned short*)Cp)[(size_t)row * 1024 + col] = f2bf(val * scale);
      } else if constexpr (MODE == 1) {
        if (!vmode)
          ((unsigned short*)Cp)[(size_t)row * 64 + col] = f2bf(val);
        else  // vprojT[b][d=col][n]
          ((unsigned short*)Cp)[(size_t)(row >> 11) * (64 * 2048) +
                                (size_t)col * 2048 + (row & 2047)] = f2bf(val);
      } else { // out (N,B,C) f32
        ((float*)Cp)[(size_t)(row & 2047) * 2048 + (size_t)(row >> 11) * 1024 + col] = val;
      }
    }
  }
}

// ---------------- flash attention (MQA), swapped-operand 32x32 MFMA ---------
// Round 3: 4 waves x 32 q-rows (grid 16x32 = 512 blocks, 2 blocks/CU).
// Double-buffered K/V (reg-staged, padded LDS), ONE barrier per KV-tile,
// global loads issued at tile top (latency hidden under compute).
// P round-trip is wave-private (no barrier). cvt_pk P->bf16. Defer-max (THR=8).
__global__ __launch_bounds__(256) void attn_kernel(
    const unsigned short* __restrict__ qp, const unsigned short* __restrict__ kp,
    const unsigned short* __restrict__ vpt, unsigned short* __restrict__ xout)
{
  constexpr int KSTR = 72;                     // 64 + 8 pad (shorts)
  __shared__ unsigned short Ks[2][64 * KSTR];  // [kv][d], double-buffered
  __shared__ unsigned short Vt[2][64 * KSTR];  // [d][kv], double-buffered
  __shared__ unsigned short Pl[4][32 * KSTR];  // per-wave P[q][kv]

  const int tid = threadIdx.x;
  const int lane = tid & 63, wave = tid >> 6;  // 4 waves
  const int lq = lane & 31, hi = lane >> 5;
  const int b = blockIdx.y >> 4, h = blockIdx.y & 15;
  const int q0 = blockIdx.x * 128 + wave * 32;
  const size_t qrow = (size_t)(b * 2048 + q0 + lq);

  unsigned short* Pw = Pl[wave];

  s16x8 qf[4];  // Q as B-operand: lane holds Q[q][d = s*16 + 8*hi .. +8)
#pragma unroll
  for (int s = 0; s < 4; ++s)
    qf[s] = *(const s16x8*)(qp + qrow * 1024 + h * 64 + s * 16 + hi * 8);

  f32x16 xacc0 = zero16(), xacc1 = zero16();
  float mrun = -1e30f, ssum = 0.f;

  const unsigned short* kb = kp + (size_t)b * (2048 * 64);
  const unsigned short* vb = vpt + (size_t)b * (64 * 2048);

  const int srow = tid >> 2;            // 0..63
  const int scol = (tid & 3) * 16;      // shorts; 32B per thread (2x b128)

  s16x8 kr0, kr1, vr0, vr1;
  {   // prologue: tile 0 -> regs -> buf 0
    const unsigned short* ks = kb + (size_t)srow * 64 + scol;
    kr0 = *(const s16x8*)ks; kr1 = *(const s16x8*)(ks + 8);
    const unsigned short* vs = vb + (size_t)srow * 2048 + scol;
    vr0 = *(const s16x8*)vs; vr1 = *(const s16x8*)(vs + 8);
    unsigned short* kd = &Ks[0][srow * KSTR + scol];
    *(s16x8*)kd = kr0; *(s16x8*)(kd + 8) = kr1;
    unsigned short* vd = &Vt[0][srow * KSTR + scol];
    *(s16x8*)vd = vr0; *(s16x8*)(vd + 8) = vr1;
  }
  int cur = 0;

  for (int t = 0; t < 32; ++t) {
    __syncthreads();   // buf[cur] ready for all; buf[cur^1] free for all
    if (t + 1 < 32) {  // issue next tile's global loads (hidden under compute)
      const unsigned short* ks = kb + (size_t)((t + 1) * 64 + srow) * 64 + scol;
      kr0 = *(const s16x8*)ks; kr1 = *(const s16x8*)(ks + 8);
      const unsigned short* vs = vb + (size_t)srow * 2048 + (t + 1) * 64 + scol;
      vr0 = *(const s16x8*)vs; vr1 = *(const s16x8*)(vs + 8);
    }
    const unsigned short* Kc = Ks[cur];
    const unsigned short* Vc = Vt[cur];

    // S^T[kv][q], two 32-kv fragments
    f32x16 sacc0 = zero16(), sacc1 = zero16();
#pragma unroll
    for (int s = 0; s < 4; ++s) {
      int c = s * 16 + hi * 8;
      s16x8 kf0 = *(const s16x8*)(Kc + lq * KSTR + c);
      s16x8 kf1 = *(const s16x8*)(Kc + (32 + lq) * KSTR + c);
      sacc0 = mfma32(kf0, qf[s], sacc0);
      sacc1 = mfma32(kf1, qf[s], sacc1);
    }

    // online softmax, exp2 domain (scale folded into q-proj), defer-max THR=8
    float tm = fmaxf(max16(sacc0), max16(sacc1));
    tm = fmaxf(tm, __shfl_xor(tm, 32));
    if (!__all(tm <= mrun + 8.f)) {
      float mnew = fmaxf(mrun, tm);
      float alpha = __builtin_amdgcn_exp2f(mrun - mnew);
      ssum *= alpha;
#pragma unroll
      for (int e = 0; e < 16; ++e) { xacc0[e] *= alpha; xacc1[e] *= alpha; }
      mrun = mnew;
    }
    f32x16 p0, p1;
#pragma unroll
    for (int e = 0; e < 16; ++e) p0[e] = __builtin_amdgcn_exp2f(sacc0[e] - mrun);
#pragma unroll
    for (int e = 0; e < 16; ++e) p1[e] = __builtin_amdgcn_exp2f(sacc1[e] - mrun);
    float tsum = sum16(p0) + sum16(p1);
    tsum += __shfl_xor(tsum, 32);
    ssum += tsum;

    // P round-trip through LDS (wave-private -> no block barrier needed).
    // sacc element e -> kv = (e&3) + 8*(e>>2) + 4*hi (+32 for p1).
#pragma unroll
    for (int g = 0; g < 4; ++g) {
      u64 w0 = ((u64)cvtpk(p0[4*g+2], p0[4*g+3]) << 32) | cvtpk(p0[4*g+0], p0[4*g+1]);
      *(u64*)(Pw + lq * KSTR + 8 * g + 4 * hi) = w0;
      u64 w1 = ((u64)cvtpk(p1[4*g+2], p1[4*g+3]) << 32) | cvtpk(p1[4*g+0], p1[4*g+1]);
      *(u64*)(Pw + lq * KSTR + 32 + 8 * g + 4 * hi) = w1;
    }

    // X^T += V^T @ P^T  (two 32-d fragments)
#pragma unroll
    for (int kvs = 0; kvs < 4; ++kvs) {
      int c = kvs * 16 + hi * 8;
      s16x8 vf0 = *(const s16x8*)(Vc + lq * KSTR + c);
      s16x8 vf1 = *(const s16x8*)(Vc + (32 + lq) * KSTR + c);
      s16x8 pf  = *(const s16x8*)(Pw + lq * KSTR + c);
      xacc0 = mfma32(vf0, pf, xacc0);
      xacc1 = mfma32(vf1, pf, xacc1);
    }

    if (t + 1 < 32) {  // write staged regs -> other buffer; visible after next barrier
      unsigned short* kd = &Ks[cur ^ 1][srow * KSTR + scol];
      *(s16x8*)kd = kr0; *(s16x8*)(kd + 8) = kr1;
      unsigned short* vd = &Vt[cur ^ 1][srow * KSTR + scol];
      *(s16x8*)vd = vr0; *(s16x8*)(vd + 8) = vr1;
      cur ^= 1;
    }
  }

  float inv = 1.0f / ssum;
#pragma unroll
  for (int dj = 0; dj < 2; ++dj) {
    const f32x16 xa = dj ? xacc1 : xacc0;
#pragma unroll
    for (int g = 0; g < 4; ++g) {
      u16x4 o4;
#pragma unroll
      for (int r = 0; r < 4; ++r) o4[r] = f2bf(xa[g * 4 + r] * inv);
      int d0 = dj * 32 + 8 * g + 4 * hi;
      *(u16x4*)(xout + qrow * 1024 + h * 64 + d0) = o4;
    }
  }
}

// -----------------------------------------------------------------------------
extern "C" void kernel_launch(void* const* d_in, const int* in_sizes, int n_in,
                              void* d_out, int out_size, void* d_ws, size_t ws_size,
                              hipStream_t stream)
{
  const float* query = (const float*)d_in[0];
  const float* key   = (const float*)d_in[1];
  const float* value = (const float*)d_in[2];
  const float* Wq = (const float*)d_in[4];
  const float* bq = (const float*)d_in[5];
  const float* Wk = (const float*)d_in[6];
  const float* bk = (const float*)d_in[7];
  const float* Wv = (const float*)d_in[8];
  const float* bv = (const float*)d_in[9];
  const float* Wp = (const float*)d_in[10];
  const float* bp = (const float*)d_in[11];

  char* ws = (char*)d_ws;
  unsigned short* WqT    = (unsigned short*)(ws);
  unsigned short* WpT    = (unsigned short*)(ws + (2u << 20));
  unsigned short* WkT    = (unsigned short*)(ws + (4u << 20));
  unsigned short* WvT    = (unsigned short*)(ws + (4u << 20) + (128u << 10));
  unsigned short* kproj  = (unsigned short*)(ws + (5u << 20));
  unsigned short* vprojT = (unsigned short*)(ws + (5u << 20) + (512u << 10));
  unsigned short* qproj  = (unsigned short*)(ws + (6u << 20));
  unsigned short* xbuf   = (unsigned short*)(ws + (14u << 20));

  wconv_kernel<<<dim3(1088), 256, 0, stream>>>(Wq, Wk, Wv, Wp, WqT, WkT, WvT, WpT);

  const float qscale = 0.18033688011112042f;  // hd^-0.5 * log2(e)
  gemm_kernel<64, 128, 0><<<dim3(64, 8), 256, 0, stream>>>(
      query, WqT, bq, qproj, nullptr, nullptr, nullptr, nullptr, qscale);
  gemm_kernel<64, 64, 1><<<dim3(64, 2), 256, 0, stream>>>(
      key, WkT, bk, kproj, value, WvT, bv, vprojT, 1.0f);
  attn_kernel<<<dim3(16, 32), 256, 0, stream>>>(qproj, kproj, vprojT, xbuf);
  gemm_kernel<64, 128, 2><<<dim3(64, 8), 256, 0, stream>>>(
      xbuf, WpT, bp, d_out, nullptr, nullptr, nullptr, nullptr, 1.0f);
}

// Round 4
// 144.843 us; speedup vs baseline: 1.1739x; 1.0395x over previous
//
#include <hip/hip_runtime.h>
#include <hip/hip_bf16.h>

#define DI __device__ __forceinline__

typedef float f32x4 __attribute__((ext_vector_type(4)));
typedef float f32x16 __attribute__((ext_vector_type(16)));
typedef short s16x8 __attribute__((ext_vector_type(8)));
typedef unsigned short u16x4 __attribute__((ext_vector_type(4)));
typedef unsigned long long u64;

// Problem constants: N=2048, B=2, C=1024, H=16, HD=64, M=B*N=4096.

DI unsigned short f2bf(float x) {            // f32 -> bf16 RNE (epilogue use)
  union { float f; unsigned u; } v; v.f = x;
  unsigned r = 0x7fffu + ((v.u >> 16) & 1u);
  return (unsigned short)((v.u + r) >> 16);
}

DI unsigned cvtpk(float lo, float hi) {      // packed f32x2 -> bf16x2 (RNE)
  unsigned u;
  asm("v_cvt_pk_bf16_f32 %0, %1, %2" : "=v"(u) : "v"(lo), "v"(hi));
  return u;
}

DI f32x16 zero16() {
  f32x16 z;
#pragma unroll
  for (int i = 0; i < 16; ++i) z[i] = 0.f;
  return z;
}

DI float max16(const f32x16& a) {            // 4-level tree
  float m0 = fmaxf(a[0], a[1]),  m1 = fmaxf(a[2], a[3]);
  float m2 = fmaxf(a[4], a[5]),  m3 = fmaxf(a[6], a[7]);
  float m4 = fmaxf(a[8], a[9]),  m5 = fmaxf(a[10], a[11]);
  float m6 = fmaxf(a[12], a[13]), m7 = fmaxf(a[14], a[15]);
  m0 = fmaxf(m0, m1); m2 = fmaxf(m2, m3); m4 = fmaxf(m4, m5); m6 = fmaxf(m6, m7);
  return fmaxf(fmaxf(m0, m2), fmaxf(m4, m6));
}

DI float sum16(const f32x16& a) {            // 4-level tree
  float s0 = a[0] + a[1],  s1 = a[2] + a[3];
  float s2 = a[4] + a[5],  s3 = a[6] + a[7];
  float s4 = a[8] + a[9],  s5 = a[10] + a[11];
  float s6 = a[12] + a[13], s7 = a[14] + a[15];
  s0 += s1; s2 += s3; s4 += s5; s6 += s7;
  return (s0 + s2) + (s4 + s6);
}

DI void gll16(const void* g, void* l) {      // async global->LDS, 16B/lane
  __builtin_amdgcn_global_load_lds(
      (const __attribute__((address_space(1))) void*)g,
      (__attribute__((address_space(3))) void*)l, 16, 0, 0);
}

DI f32x16 mfma32(s16x8 a, s16x8 b, f32x16 c) {
  return __builtin_amdgcn_mfma_f32_32x32x16_bf16(a, b, c, 0, 0, 0);
}

// ---------------- weight transpose + bf16 convert ----------------
// WT[n][k] = bf16(W[k][n]); K=1024 always. Grid: 512(Wq)+512(Wp)+32(Wk)+32(Wv).
__global__ __launch_bounds__(256) void wconv_kernel(
    const float* __restrict__ Wq, const float* __restrict__ Wk,
    const float* __restrict__ Wv, const float* __restrict__ Wp,
    unsigned short* __restrict__ WqT, unsigned short* __restrict__ WkT,
    unsigned short* __restrict__ WvT, unsigned short* __restrict__ WpT)
{
  int bid = blockIdx.x;
  const float* W; unsigned short* WT; int Ncols; int base;
  if (bid < 512)       { W = Wq; WT = WqT; Ncols = 1024; base = bid; }
  else if (bid < 1024) { W = Wp; WT = WpT; Ncols = 1024; base = bid - 512; }
  else if (bid < 1056) { W = Wk; WT = WkT; Ncols = 64;   base = bid - 1024; }
  else                 { W = Wv; WT = WvT; Ncols = 64;   base = bid - 1056; }
  int nb = base >> 5, kb = base & 31;              // 64-n x 32-k tile
  int n = nb * 64 + (threadIdx.x & 63);
  int k = kb * 32 + (threadIdx.x >> 6) * 8;
  float f[8];
#pragma unroll
  for (int i = 0; i < 8; ++i) f[i] = W[(size_t)(k + i) * Ncols + n];
  union { unsigned u[4]; s16x8 v; } x;
#pragma unroll
  for (int i = 0; i < 4; ++i) x.u[i] = cvtpk(f[2 * i], f[2 * i + 1]);
  *(s16x8*)(WT + (size_t)n * 1024 + k) = x.v;
}

// ---------------- GEMM: C[M=4096][Nout] = A[4096][1024] @ WT^T (+bias) ------
// MODE 0: q-proj  (A=query f32, seq-first remap, out bf16 * scale)
// MODE 1: k/v-proj (blockIdx.y: 0 -> key remap -> kproj; 1 -> value -> vprojT)
// MODE 2: out-proj (A=x bf16 via global_load_lds, out f32 remapped to (N,B,C))
template<int BM, int BN, int MODE>
__global__ __launch_bounds__(256) void gemm_kernel(
    const void* __restrict__ Ap, const unsigned short* __restrict__ Btp,
    const float* __restrict__ biasp, void* __restrict__ Cpv,
    const void* __restrict__ Ap2, const unsigned short* __restrict__ Btp2,
    const float* __restrict__ bias2, void* __restrict__ Cpv2,
    float scale)
{
  __shared__ unsigned short Asub[BM * 64];   // [m][k]
  __shared__ unsigned short Bsub[BN * 64];   // [n][k]

  const int tid = threadIdx.x;
  const int lane = tid & 63, wave = tid >> 6;
  const int lq = lane & 31, hi = lane >> 5;
  const int wr = wave >> 1, wc = wave & 1;    // 2x2 wave grid
  constexpr int WROWS = BM / 2;
  constexpr int WCOLS = BN / 2;
  constexpr int MI = WROWS / 32;
  constexpr int NJ = WCOLS / 32;

  const void* A_ = Ap; const unsigned short* Bt = Btp;
  const float* bias = biasp; void* Cp = Cpv;
  bool vmode = false;
  if constexpr (MODE == 1) {
    if (blockIdx.y != 0) { A_ = Ap2; Bt = Btp2; bias = bias2; Cp = Cpv2; vmode = true; }
  }
  const int row0 = blockIdx.x * BM;
  const int col0 = (MODE == 1) ? 0 : blockIdx.y * BN;

  const float* Af = (const float*)A_;
  const unsigned short* Ab = (const unsigned short*)A_;
  const bool remap = (MODE == 0) || (MODE == 1 && !vmode);  // (N,B,C) -> (B,N,C) row remap

  f32x16 acc[MI][NJ];
#pragma unroll
  for (int mi = 0; mi < MI; ++mi)
#pragma unroll
    for (int nj = 0; nj < NJ; ++nj) acc[mi][nj] = zero16();

  const int ar = tid >> 4;
  const int ac = (tid & 15) * 4;

  for (int kt = 0; kt < 16; ++kt) {
    const int k0 = kt * 64;
    __syncthreads();
    if constexpr (MODE != 2) {
      // reg-staged A: f32 -> bf16 (cvt_pk) -> LDS
#pragma unroll
      for (int p = 0; p < BM / 16; ++p) {
        int r = p * 16 + ar;
        int gm = row0 + r;
        size_t grow = remap ? (size_t)((gm & 2047) * 2 + (gm >> 11)) * 1024
                            : (size_t)gm * 1024;
        f32x4 v = *(const f32x4*)(Af + grow + k0 + ac);
        u64 w = ((u64)cvtpk(v.z, v.w) << 32) | cvtpk(v.x, v.y);
        *(u64*)(&Asub[r * 64 + ac]) = w;
      }
    } else {
#pragma unroll
      for (int i = 0; i < BM / 32; ++i) {
        int o = i * 4096 + tid * 16;
        int r = o >> 7, c = (o & 127) >> 1;
        gll16(Ab + (size_t)(row0 + r) * 1024 + k0 + c,
              (char*)Asub + i * 4096 + wave * 1024);
      }
    }
#pragma unroll
    for (int i = 0; i < BN / 32; ++i) {
      int o = i * 4096 + tid * 16;
      int r = o >> 7, c = (o & 127) >> 1;
      gll16(Bt + (size_t)(col0 + r) * 1024 + k0 + c,
            (char*)Bsub + i * 4096 + wave * 1024);
    }
    __syncthreads();
#pragma unroll
    for (int s = 0; s < 4; ++s) {
      s16x8 af[MI]; s16x8 bfr[NJ];
#pragma unroll
      for (int mi = 0; mi < MI; ++mi)
        af[mi] = *(const s16x8*)((const char*)Asub +
                  (wr * WROWS + mi * 32 + lq) * 128 + s * 32 + hi * 16);
#pragma unroll
      for (int nj = 0; nj < NJ; ++nj)
        bfr[nj] = *(const s16x8*)((const char*)Bsub +
                  (wc * WCOLS + nj * 32 + lq) * 128 + s * 32 + hi * 16);
#pragma unroll
      for (int mi = 0; mi < MI; ++mi)
#pragma unroll
        for (int nj = 0; nj < NJ; ++nj)
          acc[mi][nj] = mfma32(af[mi], bfr[nj], acc[mi][nj]);
    }
  }

  // epilogue; C-layout: col = lane&31, row = (e&3) + 8*(e>>2) + 4*(lane>>5)
#pragma unroll
  for (int mi = 0; mi < MI; ++mi)
#pragma unroll
  for (int nj = 0; nj < NJ; ++nj) {
    int col = col0 + wc * WCOLS + nj * 32 + lq;
    float bv = bias[col];
#pragma unroll
    for (int g = 0; g < 4; ++g)
#pragma unroll
    for (int r = 0; r < 4; ++r) {
      int e = g * 4 + r;
      int row = row0 + wr * WROWS + mi * 32 + r + 8 * g + 4 * hi;
      float val = acc[mi][nj][e] + bv;
      if constexpr (MODE == 0) {
        ((unsigned short*)Cp)[(size_t)row * 1024 + col] = f2bf(val * scale);
      } else if constexpr (MODE == 1) {
        if (!vmode)
          ((unsigned short*)Cp)[(size_t)row * 64 + col] = f2bf(val);
        else  // vprojT[b][d=col][n]
          ((unsigned short*)Cp)[(size_t)(row >> 11) * (64 * 2048) +
                                (size_t)col * 2048 + (row & 2047)] = f2bf(val);
      } else { // out (N,B,C) f32
        ((float*)Cp)[(size_t)(row & 2047) * 2048 + (size_t)(row >> 11) * 1024 + col] = val;
      }
    }
  }
}

// ---------------- flash attention (MQA), swapped-operand 32x32 MFMA ---------
// Round 4: 8 waves/block = 4 q-subtiles x 2 KV-halves (kv-split). Waves 0-3
// process kv-tiles 0..15, waves 4-7 process 16..31; merge (m,l,X) via LDS at
// the end. In-register P (cvt_pk + cross-half shfl; bijective-sigma on both
// PV operands -> correct regardless of HW B-frag k-mapping). Double-buffered
// K/V, ONE barrier per iteration. Defer-max THR=8. setprio around MFMA.
__global__ __launch_bounds__(512, 4) void attn_kernel(
    const unsigned short* __restrict__ qp, const unsigned short* __restrict__ kp,
    const unsigned short* __restrict__ vpt, unsigned short* __restrict__ xout)
{
  constexpr int KSTR = 72;                   // 64 + 8 pad (shorts)
  // 72KB blob: K buffers [cur][half] then V buffers; merge scratch overlays.
  __shared__ unsigned short SM[36864];
#define KBUF(c, hh) (SM + ((c) * 2 + (hh)) * (64 * KSTR))
#define VBUF(c, hh) (SM + 18432 + ((c) * 2 + (hh)) * (64 * KSTR))

  const int tid = threadIdx.x;
  const int lane = tid & 63, wave = tid >> 6;  // 8 waves
  const int lq = lane & 31, hi = lane >> 5;
  const int qsub = wave & 3, half = wave >> 2;
  const int b = blockIdx.y >> 4, h = blockIdx.y & 15;
  const int q0 = blockIdx.x * 128 + qsub * 32;
  const size_t qrow = (size_t)(b * 2048 + q0 + lq);

  s16x8 qf[4];  // Q as B-operand: lane holds Q[q][d = s*16 + 8*hi .. +8)
#pragma unroll
  for (int s = 0; s < 4; ++s)
    qf[s] = *(const s16x8*)(qp + qrow * 1024 + h * 64 + s * 16 + hi * 8);

  f32x16 xacc0 = zero16(), xacc1 = zero16();
  float mrun = -1e30f, ssum = 0.f;

  const unsigned short* kb = kp + (size_t)b * (2048 * 64);
  const unsigned short* vb = vpt + (size_t)b * (64 * 2048);

  const int srow = tid >> 3;            // 0..63 (512 threads cover 64x64 tile)
  const int scol = (tid & 7) * 8;       // shorts; one 16B chunk per tile

  s16x8 kA, kB, vA, vB;
  {   // prologue: tiles 0 and 16 -> buf 0
    kA = *(const s16x8*)(kb + (size_t)srow * 64 + scol);
    kB = *(const s16x8*)(kb + (size_t)(16 * 64 + srow) * 64 + scol);
    vA = *(const s16x8*)(vb + (size_t)srow * 2048 + scol);
    vB = *(const s16x8*)(vb + (size_t)srow * 2048 + 16 * 64 + scol);
    *(s16x8*)(KBUF(0, 0) + srow * KSTR + scol) = kA;
    *(s16x8*)(KBUF(0, 1) + srow * KSTR + scol) = kB;
    *(s16x8*)(VBUF(0, 0) + srow * KSTR + scol) = vA;
    *(s16x8*)(VBUF(0, 1) + srow * KSTR + scol) = vB;
  }
  int cur = 0;

  for (int it = 0; it < 16; ++it) {
    __syncthreads();   // buf[cur] ready; buf[cur^1] free
    if (it + 1 < 16) { // issue next tile-pair loads (latency hidden under compute)
      kA = *(const s16x8*)(kb + (size_t)((it + 1) * 64 + srow) * 64 + scol);
      kB = *(const s16x8*)(kb + (size_t)((it + 17) * 64 + srow) * 64 + scol);
      vA = *(const s16x8*)(vb + (size_t)srow * 2048 + (it + 1) * 64 + scol);
      vB = *(const s16x8*)(vb + (size_t)srow * 2048 + (it + 17) * 64 + scol);
    }
    const unsigned short* Kc = KBUF(cur, half);
    const unsigned short* Vc = VBUF(cur, half);

    // S^T[kv][q], two 32-kv fragments
    f32x16 sacc0 = zero16(), sacc1 = zero16();
    __builtin_amdgcn_s_setprio(1);
#pragma unroll
    for (int s = 0; s < 4; ++s) {
      int c = s * 16 + hi * 8;
      s16x8 kf0 = *(const s16x8*)(Kc + lq * KSTR + c);
      s16x8 kf1 = *(const s16x8*)(Kc + (32 + lq) * KSTR + c);
      sacc0 = mfma32(kf0, qf[s], sacc0);
      sacc1 = mfma32(kf1, qf[s], sacc1);
    }
    __builtin_amdgcn_s_setprio(0);

    // online softmax, exp2 domain (scale folded into q-proj), defer-max THR=8
    float tm = fmaxf(max16(sacc0), max16(sacc1));
    tm = fmaxf(tm, __shfl_xor(tm, 32));
    if (!__all(tm <= mrun + 8.f)) {
      float mnew = fmaxf(mrun, tm);
      float alpha = __builtin_amdgcn_exp2f(mrun - mnew);
      ssum *= alpha;
#pragma unroll
      for (int e = 0; e < 16; ++e) { xacc0[e] *= alpha; xacc1[e] *= alpha; }
      mrun = mnew;
    }
    f32x16 p0, p1;
#pragma unroll
    for (int e = 0; e < 16; ++e) p0[e] = __builtin_amdgcn_exp2f(sacc0[e] - mrun);
#pragma unroll
    for (int e = 0; e < 16; ++e) p1[e] = __builtin_amdgcn_exp2f(sacc1[e] - mrun);
    float tsum = sum16(p0) + sum16(p1);
    tsum += __shfl_xor(tsum, 32);
    ssum += tsum;

    // In-register P^T pack. Lane holds p[e] at kv=(e&3)+8*(e>>2)+4*hi (+32 p1).
    // pb[kvs] element j must be P^T[kv = kvs*16 + hi*8 + j][q=lq].
    s16x8 pb[4];
#pragma unroll
    for (int grp = 0; grp < 4; ++grp) {       // grp: {p0,p1} x {e0-7, e8-15}
      const f32x16& pp = (grp < 2) ? p0 : p1;
      const int eb = (grp & 1) * 8;
      unsigned A  = cvtpk(pp[eb + 0], pp[eb + 1]);
      unsigned Bw = cvtpk(pp[eb + 2], pp[eb + 3]);
      unsigned Cw = cvtpk(pp[eb + 4], pp[eb + 5]);
      unsigned Dw = cvtpk(pp[eb + 6], pp[eb + 7]);
      unsigned rA = (unsigned)__shfl_xor((int)(hi ? A : Cw), 32);
      unsigned rB = (unsigned)__shfl_xor((int)(hi ? Bw : Dw), 32);
      union { unsigned u[4]; s16x8 v; } pk_;
      pk_.u[0] = hi ? rA : A;
      pk_.u[1] = hi ? rB : Bw;
      pk_.u[2] = hi ? Cw : rA;
      pk_.u[3] = hi ? Dw : rB;
      pb[grp] = pk_.v;
    }

    // X^T += V^T @ P^T  (two 32-d fragments)
    __builtin_amdgcn_s_setprio(1);
#pragma unroll
    for (int kvs = 0; kvs < 4; ++kvs) {
      int c = kvs * 16 + hi * 8;
      s16x8 vf0 = *(const s16x8*)(Vc + lq * KSTR + c);
      s16x8 vf1 = *(const s16x8*)(Vc + (32 + lq) * KSTR + c);
      xacc0 = mfma32(vf0, pb[kvs], xacc0);
      xacc1 = mfma32(vf1, pb[kvs], xacc1);
    }
    __builtin_amdgcn_s_setprio(0);

    if (it + 1 < 16) {  // write staged regs -> other buffer
      *(s16x8*)(KBUF(cur ^ 1, 0) + srow * KSTR + scol) = kA;
      *(s16x8*)(KBUF(cur ^ 1, 1) + srow * KSTR + scol) = kB;
      *(s16x8*)(VBUF(cur ^ 1, 0) + srow * KSTR + scol) = vA;
      *(s16x8*)(VBUF(cur ^ 1, 1) + srow * KSTR + scol) = vB;
      cur ^= 1;
    }
  }

  // ---- merge the two kv-halves (pair: waves qsub & qsub+4), via LDS ----
  __syncthreads();                     // all K/V reads done; SM reusable
  float* msc = (float*)SM;             // stride 37 f32 per lane (odd -> no bank clash)
  const int mi_ = (qsub * 64 + lane) * 37;
  if (half == 1) {
#pragma unroll
    for (int e = 0; e < 16; ++e) { msc[mi_ + e] = xacc0[e]; msc[mi_ + 16 + e] = xacc1[e]; }
    msc[mi_ + 32] = mrun;
    msc[mi_ + 33] = ssum;
  }
  __syncthreads();
  if (half == 0) {
    float pm = msc[mi_ + 32], ps = msc[mi_ + 33];
    float mf = fmaxf(mrun, pm);
    float aa = __builtin_amdgcn_exp2f(mrun - mf);
    float bb = __builtin_amdgcn_exp2f(pm - mf);
    float inv = 1.0f / (ssum * aa + ps * bb);
#pragma unroll
    for (int dj = 0; dj < 2; ++dj) {
      const f32x16 xa = dj ? xacc1 : xacc0;
#pragma unroll
      for (int g = 0; g < 4; ++g) {
        u16x4 o4;
#pragma unroll
        for (int r = 0; r < 4; ++r) {
          int e = g * 4 + r;
          float merged = xa[e] * aa + msc[mi_ + dj * 16 + e] * bb;
          o4[r] = f2bf(merged * inv);
        }
        int d0 = dj * 32 + 8 * g + 4 * hi;
        *(u16x4*)(xout + qrow * 1024 + h * 64 + d0) = o4;
      }
    }
  }
#undef KBUF
#undef VBUF
}

// -----------------------------------------------------------------------------
extern "C" void kernel_launch(void* const* d_in, const int* in_sizes, int n_in,
                              void* d_out, int out_size, void* d_ws, size_t ws_size,
                              hipStream_t stream)
{
  const float* query = (const float*)d_in[0];
  const float* key   = (const float*)d_in[1];
  const float* value = (const float*)d_in[2];
  const float* Wq = (const float*)d_in[4];
  const float* bq = (const float*)d_in[5];
  const float* Wk = (const float*)d_in[6];
  const float* bk = (const float*)d_in[7];
  const float* Wv = (const float*)d_in[8];
  const float* bv = (const float*)d_in[9];
  const float* Wp = (const float*)d_in[10];
  const float* bp = (const float*)d_in[11];

  char* ws = (char*)d_ws;
  unsigned short* WqT    = (unsigned short*)(ws);
  unsigned short* WpT    = (unsigned short*)(ws + (2u << 20));
  unsigned short* WkT    = (unsigned short*)(ws + (4u << 20));
  unsigned short* WvT    = (unsigned short*)(ws + (4u << 20) + (128u << 10));
  unsigned short* kproj  = (unsigned short*)(ws + (5u << 20));
  unsigned short* vprojT = (unsigned short*)(ws + (5u << 20) + (512u << 10));
  unsigned short* qproj  = (unsigned short*)(ws + (6u << 20));
  unsigned short* xbuf   = (unsigned short*)(ws + (14u << 20));

  wconv_kernel<<<dim3(1088), 256, 0, stream>>>(Wq, Wk, Wv, Wp, WqT, WkT, WvT, WpT);

  const float qscale = 0.18033688011112042f;  // hd^-0.5 * log2(e)
  gemm_kernel<64, 128, 0><<<dim3(64, 8), 256, 0, stream>>>(
      query, WqT, bq, qproj, nullptr, nullptr, nullptr, nullptr, qscale);
  gemm_kernel<64, 64, 1><<<dim3(64, 2), 256, 0, stream>>>(
      key, WkT, bk, kproj, value, WvT, bv, vprojT, 1.0f);
  attn_kernel<<<dim3(16, 32), 512, 0, stream>>>(qproj, kproj, vprojT, xbuf);
  gemm_kernel<64, 128, 2><<<dim3(64, 8), 256, 0, stream>>>(
      xbuf, WpT, bp, d_out, nullptr, nullptr, nullptr, nullptr, 1.0f);
}

// Round 5
// 122.179 us; speedup vs baseline: 1.3917x; 1.1855x over previous
//
#include <hip/hip_runtime.h>
#include <hip/hip_bf16.h>

#define DI __device__ __forceinline__

typedef float f32x4 __attribute__((ext_vector_type(4)));
typedef float f32x16 __attribute__((ext_vector_type(16)));
typedef short s16x8 __attribute__((ext_vector_type(8)));
typedef unsigned short u16x4 __attribute__((ext_vector_type(4)));
typedef unsigned long long u64;

// Problem constants: N=2048, B=2, C=1024, H=16, HD=64, M=B*N=4096.

DI unsigned short f2bf(float x) {            // f32 -> bf16 RNE (epilogue use)
  union { float f; unsigned u; } v; v.f = x;
  unsigned r = 0x7fffu + ((v.u >> 16) & 1u);
  return (unsigned short)((v.u + r) >> 16);
}

DI unsigned cvtpk(float lo, float hi) {      // packed f32x2 -> bf16x2 (RNE)
  unsigned u;
  asm("v_cvt_pk_bf16_f32 %0, %1, %2" : "=v"(u) : "v"(lo), "v"(hi));
  return u;
}

DI f32x16 zero16() {
  f32x16 z;
#pragma unroll
  for (int i = 0; i < 16; ++i) z[i] = 0.f;
  return z;
}

DI float max16(const f32x16& a) {            // 4-level tree
  float m0 = fmaxf(a[0], a[1]),  m1 = fmaxf(a[2], a[3]);
  float m2 = fmaxf(a[4], a[5]),  m3 = fmaxf(a[6], a[7]);
  float m4 = fmaxf(a[8], a[9]),  m5 = fmaxf(a[10], a[11]);
  float m6 = fmaxf(a[12], a[13]), m7 = fmaxf(a[14], a[15]);
  m0 = fmaxf(m0, m1); m2 = fmaxf(m2, m3); m4 = fmaxf(m4, m5); m6 = fmaxf(m6, m7);
  return fmaxf(fmaxf(m0, m2), fmaxf(m4, m6));
}

DI float sum16(const f32x16& a) {            // 4-level tree
  float s0 = a[0] + a[1],  s1 = a[2] + a[3];
  float s2 = a[4] + a[5],  s3 = a[6] + a[7];
  float s4 = a[8] + a[9],  s5 = a[10] + a[11];
  float s6 = a[12] + a[13], s7 = a[14] + a[15];
  s0 += s1; s2 += s3; s4 += s5; s6 += s7;
  return (s0 + s2) + (s4 + s6);
}

DI void gll16(const void* g, void* l) {      // async global->LDS, 16B/lane
  __builtin_amdgcn_global_load_lds(
      (const __attribute__((address_space(1))) void*)g,
      (__attribute__((address_space(3))) void*)l, 16, 0, 0);
}

DI f32x16 mfma32(s16x8 a, s16x8 b, f32x16 c) {
  return __builtin_amdgcn_mfma_f32_32x32x16_bf16(a, b, c, 0, 0, 0);
}

DI f32x4 mfma16(s16x8 a, s16x8 b, f32x4 c) {
  return __builtin_amdgcn_mfma_f32_16x16x32_bf16(a, b, c, 0, 0, 0);
}

// ---------------- weight transpose + bf16 convert ----------------
// WT[n][k] = bf16(W[k][n]); K=1024 always. Grid: 512(Wq)+512(Wp)+32(Wk)+32(Wv).
__global__ __launch_bounds__(256) void wconv_kernel(
    const float* __restrict__ Wq, const float* __restrict__ Wk,
    const float* __restrict__ Wv, const float* __restrict__ Wp,
    unsigned short* __restrict__ WqT, unsigned short* __restrict__ WkT,
    unsigned short* __restrict__ WvT, unsigned short* __restrict__ WpT)
{
  int bid = blockIdx.x;
  const float* W; unsigned short* WT; int Ncols; int base;
  if (bid < 512)       { W = Wq; WT = WqT; Ncols = 1024; base = bid; }
  else if (bid < 1024) { W = Wp; WT = WpT; Ncols = 1024; base = bid - 512; }
  else if (bid < 1056) { W = Wk; WT = WkT; Ncols = 64;   base = bid - 1024; }
  else                 { W = Wv; WT = WvT; Ncols = 64;   base = bid - 1056; }
  int nb = base >> 5, kb = base & 31;              // 64-n x 32-k tile
  int n = nb * 64 + (threadIdx.x & 63);
  int k = kb * 32 + (threadIdx.x >> 6) * 8;
  float f[8];
#pragma unroll
  for (int i = 0; i < 8; ++i) f[i] = W[(size_t)(k + i) * Ncols + n];
  union { unsigned u[4]; s16x8 v; } x;
#pragma unroll
  for (int i = 0; i < 4; ++i) x.u[i] = cvtpk(f[2 * i], f[2 * i + 1]);
  *(s16x8*)(WT + (size_t)n * 1024 + k) = x.v;
}

// ---------------- activation f32 -> bf16 (+ seq-first remap) ----------------
// qbf/kbf[row=b*2048+n][c] = bf16(query/key[n][b][c]); vbf[row][c] = bf16(value).
__global__ __launch_bounds__(256) void cvt3_kernel(
    const float* __restrict__ q, const float* __restrict__ k,
    const float* __restrict__ v, unsigned short* __restrict__ qbf,
    unsigned short* __restrict__ kbf, unsigned short* __restrict__ vbf)
{
  int gid = blockIdx.x * 256 + threadIdx.x;    // 3 * 524288 threads
  int which = gid >> 19;
  int idx = gid & 524287;
  int row = idx >> 7;
  int c8 = (idx & 127) << 3;
  const float* src; unsigned short* dst; size_t soff;
  if (which == 0)      { src = q; dst = qbf; }
  else if (which == 1) { src = k; dst = kbf; }
  else                 { src = v; dst = vbf; }
  if (which < 2) {
    int b = row >> 11, n = row & 2047;
    soff = ((size_t)n * 2 + b) * 1024 + c8;
  } else {
    soff = (size_t)row * 1024 + c8;
  }
  f32x4 v0 = *(const f32x4*)(src + soff);
  f32x4 v1 = *(const f32x4*)(src + soff + 4);
  union { unsigned u[4]; s16x8 v; } x;
  x.u[0] = cvtpk(v0.x, v0.y); x.u[1] = cvtpk(v0.z, v0.w);
  x.u[2] = cvtpk(v1.x, v1.y); x.u[3] = cvtpk(v1.z, v1.w);
  *(s16x8*)(dst + (size_t)row * 1024 + c8) = x.v;
}

// ---------------- GEMM16: C[M=4096][Nout] = A[4096][1024] @ WT^T (+bias) ----
// 16x16x32 MFMA, m97 fragment economics. A,B both bf16 via global_load_lds.
// MODE 0: qproj  (out bf16, (acc+bias)*scale)
// MODE 1: kv-proj partials (blockIdx.y selects k/v; blockIdx.z = K-split chunk)
// MODE 2: out-proj (out f32 remapped to (N,B,C), +bias)
template<int BM, int BN, int MODE, int KSPLIT>
__global__ __launch_bounds__(256) void gemm16_kernel(
    const unsigned short* __restrict__ A1, const unsigned short* __restrict__ A2,
    const unsigned short* __restrict__ B1, const unsigned short* __restrict__ B2,
    const float* __restrict__ bias, void* __restrict__ Cpv, float scale)
{
  __shared__ unsigned short Asub[BM * 64];
  __shared__ unsigned short Bsub[BN * 64];

  const int tid = threadIdx.x;
  const int lane = tid & 63, wave = tid >> 6;
  const int l16 = lane & 15, kq = lane >> 4;    // kq in 0..3
  const int wr = wave >> 1, wc = wave & 1;      // 2x2 wave grid
  constexpr int WROWS = BM / 2, WCOLS = BN / 2;
  constexpr int MI = WROWS / 16, NJ = WCOLS / 16;

  const unsigned short* A = A1; const unsigned short* Bt = B1;
  int sel = 0;
  if constexpr (MODE == 1) {
    sel = blockIdx.y;
    if (sel) { A = A2; Bt = B2; }
  }
  const int row0 = blockIdx.x * BM;
  const int col0 = (MODE == 1) ? 0 : blockIdx.y * BN;
  const int kt0 = (KSPLIT > 1) ? blockIdx.z * (16 / KSPLIT) : 0;
  const int kt1 = kt0 + 16 / KSPLIT;

  f32x4 acc[MI][NJ];
#pragma unroll
  for (int mi = 0; mi < MI; ++mi)
#pragma unroll
    for (int nj = 0; nj < NJ; ++nj) acc[mi][nj] = f32x4{0.f, 0.f, 0.f, 0.f};

  for (int kt = kt0; kt < kt1; ++kt) {
    const int k0 = kt * 64;
    __syncthreads();
#pragma unroll
    for (int i = 0; i < BM / 32; ++i) {
      int o = i * 4096 + tid * 16;
      int r = o >> 7, c = (o & 127) >> 1;
      gll16(A + (size_t)(row0 + r) * 1024 + k0 + c,
            (char*)Asub + i * 4096 + wave * 1024);
    }
#pragma unroll
    for (int i = 0; i < BN / 32; ++i) {
      int o = i * 4096 + tid * 16;
      int r = o >> 7, c = (o & 127) >> 1;
      gll16(Bt + (size_t)(col0 + r) * 1024 + k0 + c,
            (char*)Bsub + i * 4096 + wave * 1024);
    }
    __syncthreads();
#pragma unroll
    for (int ks = 0; ks < 2; ++ks) {
      s16x8 af[MI]; s16x8 bfr[NJ];
#pragma unroll
      for (int mi = 0; mi < MI; ++mi)
        af[mi] = *(const s16x8*)(Asub + (wr * WROWS + mi * 16 + l16) * 64 + ks * 32 + kq * 8);
#pragma unroll
      for (int nj = 0; nj < NJ; ++nj)
        bfr[nj] = *(const s16x8*)(Bsub + (wc * WCOLS + nj * 16 + l16) * 64 + ks * 32 + kq * 8);
#pragma unroll
      for (int mi = 0; mi < MI; ++mi)
#pragma unroll
        for (int nj = 0; nj < NJ; ++nj)
          acc[mi][nj] = mfma16(af[mi], bfr[nj], acc[mi][nj]);
    }
  }

  // epilogue; 16x16 C/D: col = lane&15, row = (lane>>4)*4 + r  [m89-verified]
#pragma unroll
  for (int mi = 0; mi < MI; ++mi)
#pragma unroll
  for (int nj = 0; nj < NJ; ++nj) {
    int col = col0 + wc * WCOLS + nj * 16 + l16;
    int rowb = row0 + wr * WROWS + mi * 16 + kq * 4;
    float bv = (MODE == 1) ? 0.f : bias[col];
#pragma unroll
    for (int r = 0; r < 4; ++r) {
      int row = rowb + r;
      float val = acc[mi][nj][r] + bv;
      if constexpr (MODE == 0) {
        ((unsigned short*)Cpv)[(size_t)row * 1024 + col] = f2bf(val * scale);
      } else if constexpr (MODE == 1) {
        ((float*)Cpv)[(((size_t)blockIdx.z * 2 + sel) * 4096 + row) * 64 + col] = val;
      } else {
        ((float*)Cpv)[(size_t)(row & 2047) * 2048 + (size_t)(row >> 11) * 1024 + col] = val;
      }
    }
  }
}

// ---------------- kv split-K reduce: partials -> kproj / vprojT (+bias) -----
__global__ __launch_bounds__(256) void kvreduce_kernel(
    const float* __restrict__ part, const float* __restrict__ bk,
    const float* __restrict__ bv, unsigned short* __restrict__ kproj,
    unsigned short* __restrict__ vprojT)
{
  int gid = blockIdx.x * 256 + threadIdx.x;    // 0 .. 524287
  int kv = gid >> 18;
  int rem = gid & 262143;
  int row = rem >> 6, col = rem & 63;
  float s = 0.f;
#pragma unroll
  for (int z = 0; z < 4; ++z)
    s += part[(((size_t)z * 2 + kv) * 4096 + row) * 64 + col];
  s += (kv ? bv : bk)[col];
  if (kv == 0)
    kproj[(size_t)row * 64 + col] = f2bf(s);
  else
    vprojT[(size_t)(row >> 11) * 131072 + (size_t)col * 2048 + (row & 2047)] = f2bf(s);
}

// ---------------- flash attention (MQA), swapped-operand 32x32 MFMA ---------
// (unchanged from round 4): 8 waves = 4 q-subtiles x 2 KV-halves, in-register
// P pack, double-buffered K/V, one barrier/iter, defer-max, setprio.
__global__ __launch_bounds__(512, 4) void attn_kernel(
    const unsigned short* __restrict__ qp, const unsigned short* __restrict__ kp,
    const unsigned short* __restrict__ vpt, unsigned short* __restrict__ xout)
{
  constexpr int KSTR = 72;                   // 64 + 8 pad (shorts)
  __shared__ unsigned short SM[36864];
#define KBUF(c, hh) (SM + ((c) * 2 + (hh)) * (64 * KSTR))
#define VBUF(c, hh) (SM + 18432 + ((c) * 2 + (hh)) * (64 * KSTR))

  const int tid = threadIdx.x;
  const int lane = tid & 63, wave = tid >> 6;  // 8 waves
  const int lq = lane & 31, hi = lane >> 5;
  const int qsub = wave & 3, half = wave >> 2;
  const int b = blockIdx.y >> 4, h = blockIdx.y & 15;
  const int q0 = blockIdx.x * 128 + qsub * 32;
  const size_t qrow = (size_t)(b * 2048 + q0 + lq);

  s16x8 qf[4];  // Q as B-operand: lane holds Q[q][d = s*16 + 8*hi .. +8)
#pragma unroll
  for (int s = 0; s < 4; ++s)
    qf[s] = *(const s16x8*)(qp + qrow * 1024 + h * 64 + s * 16 + hi * 8);

  f32x16 xacc0 = zero16(), xacc1 = zero16();
  float mrun = -1e30f, ssum = 0.f;

  const unsigned short* kb = kp + (size_t)b * (2048 * 64);
  const unsigned short* vb = vpt + (size_t)b * (64 * 2048);

  const int srow = tid >> 3;            // 0..63 (512 threads cover 64x64 tile)
  const int scol = (tid & 7) * 8;       // shorts; one 16B chunk per tile

  s16x8 kA, kB, vA, vB;
  {   // prologue: tiles 0 and 16 -> buf 0
    kA = *(const s16x8*)(kb + (size_t)srow * 64 + scol);
    kB = *(const s16x8*)(kb + (size_t)(16 * 64 + srow) * 64 + scol);
    vA = *(const s16x8*)(vb + (size_t)srow * 2048 + scol);
    vB = *(const s16x8*)(vb + (size_t)srow * 2048 + 16 * 64 + scol);
    *(s16x8*)(KBUF(0, 0) + srow * KSTR + scol) = kA;
    *(s16x8*)(KBUF(0, 1) + srow * KSTR + scol) = kB;
    *(s16x8*)(VBUF(0, 0) + srow * KSTR + scol) = vA;
    *(s16x8*)(VBUF(0, 1) + srow * KSTR + scol) = vB;
  }
  int cur = 0;

  for (int it = 0; it < 16; ++it) {
    __syncthreads();   // buf[cur] ready; buf[cur^1] free
    if (it + 1 < 16) { // issue next tile-pair loads (latency hidden under compute)
      kA = *(const s16x8*)(kb + (size_t)((it + 1) * 64 + srow) * 64 + scol);
      kB = *(const s16x8*)(kb + (size_t)((it + 17) * 64 + srow) * 64 + scol);
      vA = *(const s16x8*)(vb + (size_t)srow * 2048 + (it + 1) * 64 + scol);
      vB = *(const s16x8*)(vb + (size_t)srow * 2048 + (it + 17) * 64 + scol);
    }
    const unsigned short* Kc = KBUF(cur, half);
    const unsigned short* Vc = VBUF(cur, half);

    // S^T[kv][q], two 32-kv fragments
    f32x16 sacc0 = zero16(), sacc1 = zero16();
    __builtin_amdgcn_s_setprio(1);
#pragma unroll
    for (int s = 0; s < 4; ++s) {
      int c = s * 16 + hi * 8;
      s16x8 kf0 = *(const s16x8*)(Kc + lq * KSTR + c);
      s16x8 kf1 = *(const s16x8*)(Kc + (32 + lq) * KSTR + c);
      sacc0 = mfma32(kf0, qf[s], sacc0);
      sacc1 = mfma32(kf1, qf[s], sacc1);
    }
    __builtin_amdgcn_s_setprio(0);

    // online softmax, exp2 domain (scale folded into q-proj), defer-max THR=8
    float tm = fmaxf(max16(sacc0), max16(sacc1));
    tm = fmaxf(tm, __shfl_xor(tm, 32));
    if (!__all(tm <= mrun + 8.f)) {
      float mnew = fmaxf(mrun, tm);
      float alpha = __builtin_amdgcn_exp2f(mrun - mnew);
      ssum *= alpha;
#pragma unroll
      for (int e = 0; e < 16; ++e) { xacc0[e] *= alpha; xacc1[e] *= alpha; }
      mrun = mnew;
    }
    f32x16 p0, p1;
#pragma unroll
    for (int e = 0; e < 16; ++e) p0[e] = __builtin_amdgcn_exp2f(sacc0[e] - mrun);
#pragma unroll
    for (int e = 0; e < 16; ++e) p1[e] = __builtin_amdgcn_exp2f(sacc1[e] - mrun);
    float tsum = sum16(p0) + sum16(p1);
    tsum += __shfl_xor(tsum, 32);
    ssum += tsum;

    // In-register P^T pack. Lane holds p[e] at kv=(e&3)+8*(e>>2)+4*hi (+32 p1).
    s16x8 pb[4];
#pragma unroll
    for (int grp = 0; grp < 4; ++grp) {       // grp: {p0,p1} x {e0-7, e8-15}
      const f32x16& pp = (grp < 2) ? p0 : p1;
      const int eb = (grp & 1) * 8;
      unsigned A  = cvtpk(pp[eb + 0], pp[eb + 1]);
      unsigned Bw = cvtpk(pp[eb + 2], pp[eb + 3]);
      unsigned Cw = cvtpk(pp[eb + 4], pp[eb + 5]);
      unsigned Dw = cvtpk(pp[eb + 6], pp[eb + 7]);
      unsigned rA = (unsigned)__shfl_xor((int)(hi ? A : Cw), 32);
      unsigned rB = (unsigned)__shfl_xor((int)(hi ? Bw : Dw), 32);
      union { unsigned u[4]; s16x8 v; } pk_;
      pk_.u[0] = hi ? rA : A;
      pk_.u[1] = hi ? rB : Bw;
      pk_.u[2] = hi ? Cw : rA;
      pk_.u[3] = hi ? Dw : rB;
      pb[grp] = pk_.v;
    }

    // X^T += V^T @ P^T  (two 32-d fragments)
    __builtin_amdgcn_s_setprio(1);
#pragma unroll
    for (int kvs = 0; kvs < 4; ++kvs) {
      int c = kvs * 16 + hi * 8;
      s16x8 vf0 = *(const s16x8*)(Vc + lq * KSTR + c);
      s16x8 vf1 = *(const s16x8*)(Vc + (32 + lq) * KSTR + c);
      xacc0 = mfma32(vf0, pb[kvs], xacc0);
      xacc1 = mfma32(vf1, pb[kvs], xacc1);
    }
    __builtin_amdgcn_s_setprio(0);

    if (it + 1 < 16) {  // write staged regs -> other buffer
      *(s16x8*)(KBUF(cur ^ 1, 0) + srow * KSTR + scol) = kA;
      *(s16x8*)(KBUF(cur ^ 1, 1) + srow * KSTR + scol) = kB;
      *(s16x8*)(VBUF(cur ^ 1, 0) + srow * KSTR + scol) = vA;
      *(s16x8*)(VBUF(cur ^ 1, 1) + srow * KSTR + scol) = vB;
      cur ^= 1;
    }
  }

  // ---- merge the two kv-halves (pair: waves qsub & qsub+4), via LDS ----
  __syncthreads();                     // all K/V reads done; SM reusable
  float* msc = (float*)SM;             // stride 37 f32 per lane
  const int mi_ = (qsub * 64 + lane) * 37;
  if (half == 1) {
#pragma unroll
    for (int e = 0; e < 16; ++e) { msc[mi_ + e] = xacc0[e]; msc[mi_ + 16 + e] = xacc1[e]; }
    msc[mi_ + 32] = mrun;
    msc[mi_ + 33] = ssum;
  }
  __syncthreads();
  if (half == 0) {
    float pm = msc[mi_ + 32], ps = msc[mi_ + 33];
    float mf = fmaxf(mrun, pm);
    float aa = __builtin_amdgcn_exp2f(mrun - mf);
    float bb = __builtin_amdgcn_exp2f(pm - mf);
    float inv = 1.0f / (ssum * aa + ps * bb);
#pragma unroll
    for (int dj = 0; dj < 2; ++dj) {
      const f32x16 xa = dj ? xacc1 : xacc0;
#pragma unroll
      for (int g = 0; g < 4; ++g) {
        u16x4 o4;
#pragma unroll
        for (int r = 0; r < 4; ++r) {
          int e = g * 4 + r;
          float merged = xa[e] * aa + msc[mi_ + dj * 16 + e] * bb;
          o4[r] = f2bf(merged * inv);
        }
        int d0 = dj * 32 + 8 * g + 4 * hi;
        *(u16x4*)(xout + qrow * 1024 + h * 64 + d0) = o4;
      }
    }
  }
#undef KBUF
#undef VBUF
}

// -----------------------------------------------------------------------------
extern "C" void kernel_launch(void* const* d_in, const int* in_sizes, int n_in,
                              void* d_out, int out_size, void* d_ws, size_t ws_size,
                              hipStream_t stream)
{
  const float* query = (const float*)d_in[0];
  const float* key   = (const float*)d_in[1];
  const float* value = (const float*)d_in[2];
  const float* Wq = (const float*)d_in[4];
  const float* bq = (const float*)d_in[5];
  const float* Wk = (const float*)d_in[6];
  const float* bk = (const float*)d_in[7];
  const float* Wv = (const float*)d_in[8];
  const float* bv = (const float*)d_in[9];
  const float* Wp = (const float*)d_in[10];
  const float* bp = (const float*)d_in[11];

  char* ws = (char*)d_ws;
  unsigned short* WqT    = (unsigned short*)(ws);
  unsigned short* WpT    = (unsigned short*)(ws + (2u << 20));
  unsigned short* WkT    = (unsigned short*)(ws + (4u << 20));
  unsigned short* WvT    = (unsigned short*)(ws + (4u << 20) + (128u << 10));
  unsigned short* kproj  = (unsigned short*)(ws + (5u << 20));
  unsigned short* vprojT = (unsigned short*)(ws + (5u << 20) + (512u << 10));
  unsigned short* qproj  = (unsigned short*)(ws + (6u << 20));     // 8.39MB
  unsigned short* xbuf   = (unsigned short*)(ws + (15u << 20));    // 8.39MB (also kv partials)
  float*          part   = (float*)xbuf;                            // dead before attn writes xbuf
  unsigned short* vbf    = (unsigned short*)(ws + (24u << 20));    // 8.39MB
  // qbf/kbf live in d_out (dead until final projection; fully rewritten each call)
  unsigned short* qbf    = (unsigned short*)d_out;
  unsigned short* kbf    = (unsigned short*)d_out + 4194304;

  wconv_kernel<<<dim3(1088), 256, 0, stream>>>(Wq, Wk, Wv, Wp, WqT, WkT, WvT, WpT);
  cvt3_kernel<<<dim3(6144), 256, 0, stream>>>(query, key, value, qbf, kbf, vbf);

  const float qscale = 0.18033688011112042f;  // hd^-0.5 * log2(e)
  gemm16_kernel<64, 64, 0, 1><<<dim3(64, 16), 256, 0, stream>>>(
      qbf, qbf, WqT, WqT, bq, qproj, qscale);
  gemm16_kernel<64, 64, 1, 4><<<dim3(64, 2, 4), 256, 0, stream>>>(
      kbf, vbf, WkT, WvT, nullptr, part, 1.0f);
  kvreduce_kernel<<<dim3(2048), 256, 0, stream>>>(part, bk, bv, kproj, vprojT);
  attn_kernel<<<dim3(16, 32), 512, 0, stream>>>(qproj, kproj, vprojT, xbuf);
  gemm16_kernel<64, 64, 2, 1><<<dim3(64, 16), 256, 0, stream>>>(
      xbuf, xbuf, WpT, WpT, bp, d_out, 1.0f);
}